// Round 1
// baseline (270.732 us; speedup 1.0000x reference)
//
#include <hip/hip_runtime.h>
#include <hip/hip_fp16.h>

constexpr int N_NODES = 50000;
constexpr int N_EDGES = 400000;
constexpr int F = 128;
constexpr int NT = 64;   // node tile per block

struct alignas(8) half4 { __half2 lo, hi; };

// Fused transform: HX = x @ W_lin^T + b ; A = HX @ W_att   (per head)
// Stored fp16, layout [node][head][128].
__global__ __launch_bounds__(256) void gat_transform(
    const float* __restrict__ x,       // [N_NODES][128]
    const float* __restrict__ W_lin,   // [2][128][128]  (o, d)
    const float* __restrict__ b_lin,   // [2][128]
    const float* __restrict__ W_att,   // [2][128][128]  (o, p)
    __half* __restrict__ HX,           // [N_NODES][2][128]
    __half* __restrict__ Amat)         // [N_NODES][2][128]
{
    __shared__ float xs[NT][F];        // 32 KB  x tile
    __shared__ float hx[NT][F];        // 32 KB  head_x tile (f32, for stage 2)
    __shared__ float wch[32][F + 4];   // 16.5 KB  W k-chunk, padded rows

    const int t = threadIdx.x;
    const int node0 = blockIdx.x * NT;

    // ---- load x tile (coalesced float4, zero-pad OOB nodes)
    #pragma unroll
    for (int i = 0; i < 8; ++i) {
        int f4 = t + i * 256;          // 0..2047 float4 slots
        int n  = f4 >> 5;              // 32 float4 per row
        int c  = (f4 & 31) << 2;
        float4 v = {0.f, 0.f, 0.f, 0.f};
        if (node0 + n < N_NODES)
            v = *(const float4*)(x + (size_t)(node0 + n) * F + c);
        *(float4*)(&xs[n][c]) = v;
    }
    __syncthreads();

    const int og = t & 31;             // output group: 4 outputs
    const int ng = t >> 5;             // node group: 8 nodes
    const int n0 = ng * 8;
    const int o0 = og * 4;

    for (int h = 0; h < 2; ++h) {
        // ================= Phase B: hx = xs @ W_lin[h]^T =================
        float acc[8][4];
        #pragma unroll
        for (int n = 0; n < 8; ++n)
            #pragma unroll
            for (int j = 0; j < 4; ++j) acc[n][j] = 0.f;

        const float* W = W_lin + h * F * F;
        for (int k0 = 0; k0 < F; k0 += 32) {
            {   // stage W[:, k0:k0+32] transposed -> wch[kk][o]
                int o  = t >> 1;
                int kb = (t & 1) << 4;
                const float* src = W + o * F + k0 + kb;
                float4 v0 = *(const float4*)(src + 0);
                float4 v1 = *(const float4*)(src + 4);
                float4 v2 = *(const float4*)(src + 8);
                float4 v3 = *(const float4*)(src + 12);
                float vv[16] = {v0.x,v0.y,v0.z,v0.w, v1.x,v1.y,v1.z,v1.w,
                                v2.x,v2.y,v2.z,v2.w, v3.x,v3.y,v3.z,v3.w};
                #pragma unroll
                for (int s = 0; s < 16; ++s) wch[kb + s][o] = vv[s];
            }
            __syncthreads();
            #pragma unroll
            for (int kk = 0; kk < 32; kk += 4) {
                float wv[4][4];
                #pragma unroll
                for (int s = 0; s < 4; ++s) {
                    float4 w4 = *(const float4*)(&wch[kk + s][o0]);
                    wv[s][0] = w4.x; wv[s][1] = w4.y; wv[s][2] = w4.z; wv[s][3] = w4.w;
                }
                #pragma unroll
                for (int n = 0; n < 8; ++n) {
                    float4 xv = *(const float4*)(&xs[n0 + n][k0 + kk]);
                    #pragma unroll
                    for (int j = 0; j < 4; ++j)
                        acc[n][j] += xv.x * wv[0][j] + xv.y * wv[1][j]
                                   + xv.z * wv[2][j] + xv.w * wv[3][j];
                }
            }
            __syncthreads();
        }
        // bias + write hx (LDS f32) + HX (global f16)
        float bj[4];
        #pragma unroll
        for (int j = 0; j < 4; ++j) bj[j] = b_lin[h * F + o0 + j];
        #pragma unroll
        for (int n = 0; n < 8; ++n) {
            float v0 = acc[n][0] + bj[0], v1 = acc[n][1] + bj[1];
            float v2 = acc[n][2] + bj[2], v3 = acc[n][3] + bj[3];
            hx[n0 + n][o0 + 0] = v0; hx[n0 + n][o0 + 1] = v1;
            hx[n0 + n][o0 + 2] = v2; hx[n0 + n][o0 + 3] = v3;
            int node = node0 + n0 + n;
            if (node < N_NODES) {
                half4 o;
                o.lo = __floats2half2_rn(v0, v1);
                o.hi = __floats2half2_rn(v2, v3);
                *(half4*)(HX + (size_t)node * 256 + h * F + o0) = o;
            }
        }
        __syncthreads();

        // ================= Phase C: A = hx @ W_att[h] =================
        #pragma unroll
        for (int n = 0; n < 8; ++n)
            #pragma unroll
            for (int j = 0; j < 4; ++j) acc[n][j] = 0.f;

        const float* Wa = W_att + h * F * F;
        for (int k0 = 0; k0 < F; k0 += 32) {
            {   // stage rows k0..k0+31 straight: wch[kk][p]
                #pragma unroll
                for (int i = 0; i < 4; ++i) {
                    int f4 = t + i * 256;      // 0..1023
                    int kk = f4 >> 5;
                    int c  = (f4 & 31) << 2;
                    *(float4*)(&wch[kk][c]) =
                        *(const float4*)(Wa + (size_t)(k0 + kk) * F + c);
                }
            }
            __syncthreads();
            #pragma unroll
            for (int kk = 0; kk < 32; kk += 4) {
                float wv[4][4];
                #pragma unroll
                for (int s = 0; s < 4; ++s) {
                    float4 w4 = *(const float4*)(&wch[kk + s][o0]);
                    wv[s][0] = w4.x; wv[s][1] = w4.y; wv[s][2] = w4.z; wv[s][3] = w4.w;
                }
                #pragma unroll
                for (int n = 0; n < 8; ++n) {
                    float4 xv = *(const float4*)(&hx[n0 + n][k0 + kk]);
                    #pragma unroll
                    for (int j = 0; j < 4; ++j)
                        acc[n][j] += xv.x * wv[0][j] + xv.y * wv[1][j]
                                   + xv.z * wv[2][j] + xv.w * wv[3][j];
                }
            }
            __syncthreads();
        }
        #pragma unroll
        for (int n = 0; n < 8; ++n) {
            int node = node0 + n0 + n;
            if (node < N_NODES) {
                half4 o;
                o.lo = __floats2half2_rn(acc[n][0], acc[n][1]);
                o.hi = __floats2half2_rn(acc[n][2], acc[n][3]);
                *(half4*)(Amat + (size_t)node * 256 + h * F + o0) = o;
            }
        }
        __syncthreads();
    }
}

// One wave per edge: lanes 0..31 -> head 0, lanes 32..63 -> head 1.
// score_sum = sum over both heads; mean = /2; sigmoid.
__global__ __launch_bounds__(256) void gat_edge(
    const int* __restrict__ ei,        // [2][N_EDGES]
    const __half* __restrict__ Amat,   // [N_NODES][2][128]
    const __half* __restrict__ HX,     // [N_NODES][2][128]
    float* __restrict__ out)           // [N_EDGES]
{
    int gid  = blockIdx.x * 256 + threadIdx.x;
    int e    = gid >> 6;
    int lane = threadIdx.x & 63;
    if (e >= N_EDGES) return;

    int r = ei[e];
    int c = ei[N_EDGES + e];

    const __half* ap = Amat + (size_t)r * 256 + lane * 4;
    const __half* hp = HX   + (size_t)c * 256 + lane * 4;
    half4 av = *(const half4*)ap;
    half4 hv = *(const half4*)hp;
    float2 al = __half22float2(av.lo), ah = __half22float2(av.hi);
    float2 hl = __half22float2(hv.lo), hh = __half22float2(hv.hi);
    float p = al.x * hl.x + al.y * hl.y + ah.x * hh.x + ah.y * hh.y;

    #pragma unroll
    for (int m = 1; m <= 32; m <<= 1) p += __shfl_xor(p, m);

    if (lane == 0) out[e] = 1.f / (1.f + __expf(-0.5f * p));
}

extern "C" void kernel_launch(void* const* d_in, const int* in_sizes, int n_in,
                              void* d_out, int out_size, void* d_ws, size_t ws_size,
                              hipStream_t stream) {
    const float* x     = (const float*)d_in[0];
    const int*   ei    = (const int*)d_in[1];
    const float* W_lin = (const float*)d_in[2];
    const float* b_lin = (const float*)d_in[3];
    const float* W_att = (const float*)d_in[4];
    float* out = (float*)d_out;

    __half* HX   = (__half*)d_ws;
    __half* Amat = HX + (size_t)N_NODES * 2 * F;   // 25.6 MB offset

    dim3 grid1((N_NODES + NT - 1) / NT);           // 782 blocks
    gat_transform<<<grid1, 256, 0, stream>>>(x, W_lin, b_lin, W_att, HX, Amat);

    dim3 grid2(N_EDGES / 4);                       // 4 edges (waves) per block
    gat_edge<<<grid2, 256, 0, stream>>>(ei, Amat, HX, out);
}

// Round 2
// 198.291 us; speedup vs baseline: 1.3653x; 1.3653x over previous
//
#include <hip/hip_runtime.h>
#include <hip/hip_fp16.h>

constexpr int N_NODES = 50000;
constexpr int N_EDGES = 400000;
constexpr int F = 128;

typedef _Float16 f16x8 __attribute__((ext_vector_type(8)));
typedef float    f32x4 __attribute__((ext_vector_type(4)));

struct alignas(8) half4 { __half2 lo, hi; };

// XOR swizzle (G4): row stride is 256 B; swap 16B-slot by row&7.
// Index in _Float16 units; xor of bits 3..5 keeps 8-half chunks aligned.
__device__ __forceinline__ int swz(int row, int colh) {
    return (row * F + colh) ^ ((row & 7) << 3);
}

// Stage f32 [128][128] W -> f16 LDS, same layout, swizzled. Coalesced.
__device__ __forceinline__ void stage_w(const float* __restrict__ W,
                                        _Float16* wbuf, int t) {
    #pragma unroll
    for (int i = 0; i < 8; ++i) {
        int idx8 = i * 256 + t;          // 0..2047 chunks of 8 halfs
        int row  = idx8 >> 4;
        int colh = (idx8 & 15) * 8;
        float4 v0 = *(const float4*)(W + row * F + colh);
        float4 v1 = *(const float4*)(W + row * F + colh + 4);
        f16x8 hv;
        hv[0] = (_Float16)v0.x; hv[1] = (_Float16)v0.y;
        hv[2] = (_Float16)v0.z; hv[3] = (_Float16)v0.w;
        hv[4] = (_Float16)v1.x; hv[5] = (_Float16)v1.y;
        hv[6] = (_Float16)v1.z; hv[7] = (_Float16)v1.w;
        *(f16x8*)(wbuf + swz(row, colh)) = hv;
    }
}

// Stage W_att transposed: wbuf[p][o] = Wa[o][p] (f16, swizzled).
// Global reads coalesced (256B/wave); LDS scalar writes ~8-way (one-time).
__device__ __forceinline__ void stage_wa_t(const float* __restrict__ Wa,
                                           _Float16* wbuf, int t) {
    #pragma unroll
    for (int i = 0; i < 64; ++i) {
        int lin = i * 256 + t;           // 0..16383
        int o = lin >> 7;
        int p = lin & 127;
        wbuf[swz(p, o)] = (_Float16)Wa[o * F + p];
    }
}

// MFMA transform: HX = x @ W_lin^T + b ; A = HX @ W_att. Output fp16,
// layout [node][head][128]. 4 waves/block, 16 nodes/wave.
__global__ __launch_bounds__(256) void gat_transform(
    const float* __restrict__ x,       // [N][128]
    const float* __restrict__ W_lin,   // [2][128][128] (o,d)
    const float* __restrict__ b_lin,   // [2][128]
    const float* __restrict__ W_att,   // [2][128][128] (o,p)
    __half* __restrict__ HX,           // [N][2][128]
    __half* __restrict__ Amat)         // [N][2][128]
{
    __shared__ _Float16 wbuf[F * F];   // 32 KB
    __shared__ _Float16 hxbuf[64 * F]; // 16 KB

    const int t    = threadIdx.x;
    const int wave = t >> 6;
    const int lane = t & 63;
    const int r16  = lane & 15;
    const int kgrp = lane >> 4;
    const int node_base = blockIdx.x * 64 + wave * 16;

    // ---- A-frags: x rows f32 -> f16 (reused across both heads)
    f16x8 af[4];
    {
        int xrow = node_base + r16;
        if (xrow >= N_NODES) xrow = N_NODES - 1;
        const float* xp = x + (size_t)xrow * F + kgrp * 8;
        #pragma unroll
        for (int kk = 0; kk < 4; ++kk) {
            float4 v0 = *(const float4*)(xp + kk * 32);
            float4 v1 = *(const float4*)(xp + kk * 32 + 4);
            f16x8 hv;
            hv[0] = (_Float16)v0.x; hv[1] = (_Float16)v0.y;
            hv[2] = (_Float16)v0.z; hv[3] = (_Float16)v0.w;
            hv[4] = (_Float16)v1.x; hv[5] = (_Float16)v1.y;
            hv[6] = (_Float16)v1.z; hv[7] = (_Float16)v1.w;
            af[kk] = hv;
        }
    }

    for (int h = 0; h < 2; ++h) {
        // ================= Phase B: HX = x @ W_lin[h]^T + b =================
        stage_w(W_lin + h * F * F, wbuf, t);
        __syncthreads();

        f32x4 acc[8];
        #pragma unroll
        for (int c = 0; c < 8; ++c) { acc[c][0]=0.f; acc[c][1]=0.f; acc[c][2]=0.f; acc[c][3]=0.f; }

        #pragma unroll
        for (int c = 0; c < 8; ++c) {
            #pragma unroll
            for (int kk = 0; kk < 4; ++kk) {
                f16x8 bf = *(const f16x8*)(wbuf + swz(c * 16 + r16, kk * 32 + kgrp * 8));
                acc[c] = __builtin_amdgcn_mfma_f32_16x16x32_f16(af[kk], bf, acc[c], 0, 0, 0);
            }
        }

        // bias + D-frag (col=lane&15,row=kgrp*4+r) -> hxbuf f16 (swizzled)
        #pragma unroll
        for (int c = 0; c < 8; ++c) {
            float bv = b_lin[h * F + c * 16 + r16];
            #pragma unroll
            for (int r = 0; r < 4; ++r)
                hxbuf[swz(wave * 16 + kgrp * 4 + r, c * 16 + r16)] =
                    (_Float16)(acc[c][r] + bv);
        }

        // coalesced HX global store from hxbuf (wave-local rows)
        #pragma unroll
        for (int i = 0; i < 4; ++i) {
            int chunk = i * 64 + lane;      // 0..255
            int lr = chunk >> 4;
            int ch = (chunk & 15) * 8;
            int node = node_base + lr;
            if (node < N_NODES) {
                f16x8 v = *(const f16x8*)(hxbuf + swz(wave * 16 + lr, ch));
                *(f16x8*)((_Float16*)HX + (size_t)node * 256 + h * F + ch) = v;
            }
        }
        __syncthreads();                    // all waves done with W_lin in wbuf

        // ================= Phase C: A = HX @ W_att[h] =================
        stage_wa_t(W_att + h * F * F, wbuf, t);
        // A-frags from hxbuf (wave-local; read before barrier is safe)
        f16x8 haf[4];
        #pragma unroll
        for (int kk = 0; kk < 4; ++kk)
            haf[kk] = *(const f16x8*)(hxbuf + swz(wave * 16 + r16, kk * 32 + kgrp * 8));
        __syncthreads();                    // Wa_t staged

        #pragma unroll
        for (int c = 0; c < 8; ++c) { acc[c][0]=0.f; acc[c][1]=0.f; acc[c][2]=0.f; acc[c][3]=0.f; }

        #pragma unroll
        for (int c = 0; c < 8; ++c) {
            #pragma unroll
            for (int kk = 0; kk < 4; ++kk) {
                f16x8 bf = *(const f16x8*)(wbuf + swz(c * 16 + r16, kk * 32 + kgrp * 8));
                acc[c] = __builtin_amdgcn_mfma_f32_16x16x32_f16(haf[kk], bf, acc[c], 0, 0, 0);
            }
        }

        // A-out -> hxbuf (overwrite ok: haf already in regs, wave-local)
        #pragma unroll
        for (int c = 0; c < 8; ++c)
            #pragma unroll
            for (int r = 0; r < 4; ++r)
                hxbuf[swz(wave * 16 + kgrp * 4 + r, c * 16 + r16)] = (_Float16)acc[c][r];

        #pragma unroll
        for (int i = 0; i < 4; ++i) {
            int chunk = i * 64 + lane;
            int lr = chunk >> 4;
            int ch = (chunk & 15) * 8;
            int node = node_base + lr;
            if (node < N_NODES) {
                f16x8 v = *(const f16x8*)(hxbuf + swz(wave * 16 + lr, ch));
                *(f16x8*)((_Float16*)Amat + (size_t)node * 256 + h * F + ch) = v;
            }
        }
        __syncthreads();                    // before next head reuses wbuf
    }
}

// One wave per edge: lane*4 f16 covers [2 heads][128]; shuffle-reduce
// sums both heads; sigmoid(0.5 * sum).
__global__ __launch_bounds__(256) void gat_edge(
    const int* __restrict__ ei,        // [2][N_EDGES]
    const __half* __restrict__ Amat,   // [N][2][128]
    const __half* __restrict__ HX,     // [N][2][128]
    float* __restrict__ out)           // [N_EDGES]
{
    int gid  = blockIdx.x * 256 + threadIdx.x;
    int e    = gid >> 6;
    int lane = threadIdx.x & 63;
    if (e >= N_EDGES) return;

    int r = ei[e];
    int c = ei[N_EDGES + e];

    half4 av = *(const half4*)(Amat + (size_t)r * 256 + lane * 4);
    half4 hv = *(const half4*)(HX   + (size_t)c * 256 + lane * 4);
    float2 al = __half22float2(av.lo), ah = __half22float2(av.hi);
    float2 hl = __half22float2(hv.lo), hh = __half22float2(hv.hi);
    float p = al.x * hl.x + al.y * hl.y + ah.x * hh.x + ah.y * hh.y;

    #pragma unroll
    for (int m = 1; m <= 32; m <<= 1) p += __shfl_xor(p, m);

    if (lane == 0) out[e] = 1.f / (1.f + __expf(-0.5f * p));
}

extern "C" void kernel_launch(void* const* d_in, const int* in_sizes, int n_in,
                              void* d_out, int out_size, void* d_ws, size_t ws_size,
                              hipStream_t stream) {
    const float* x     = (const float*)d_in[0];
    const int*   ei    = (const int*)d_in[1];
    const float* W_lin = (const float*)d_in[2];
    const float* b_lin = (const float*)d_in[3];
    const float* W_att = (const float*)d_in[4];
    float* out = (float*)d_out;

    __half* HX   = (__half*)d_ws;
    __half* Amat = HX + (size_t)N_NODES * 2 * F;   // 25.6 MB offset

    dim3 grid1((N_NODES + 63) / 64);               // 782 blocks, 64 nodes each
    gat_transform<<<grid1, 256, 0, stream>>>(x, W_lin, b_lin, W_att, HX, Amat);

    dim3 grid2(N_EDGES / 4);                       // 4 edges (waves) per block
    gat_edge<<<grid2, 256, 0, stream>>>(ei, Amat, HX, out);
}

// Round 3
// 102.664 us; speedup vs baseline: 2.6371x; 1.9315x over previous
//
#include <hip/hip_runtime.h>
#include <hip/hip_fp16.h>

constexpr int N_NODES = 50000;
constexpr int N_EDGES = 400000;
constexpr int F = 128;

typedef _Float16 f16x8 __attribute__((ext_vector_type(8)));
typedef _Float16 f16x4 __attribute__((ext_vector_type(4)));
typedef float    f32x4 __attribute__((ext_vector_type(4)));

// XOR swizzle: flips half-index bits 3..5 (byte bits 4..6) by row&7 so the
// 16 rows a frag-read touches spread across all 32 banks. 16B chunks stay aligned.
__device__ __forceinline__ int swz(int row, int colh) {
    return (row * F + colh) ^ ((row & 7) << 3);
}

// ---------------- Kernel 1: weight fusion (tiny) ----------------
// Wall slots (f16 [128][128], natural [o][d]):
//   0: W_lin[0], 1: Wf[0]=W_att[0]@W_lin[0], 2: W_lin[1], 3: Wf[1]
// ball slots (f32 [128]): 0: b[0], 1: W_att[0]@b[0], 2: b[1], 3: W_att[1]@b[1]
// Then HX = x@W_lin[h]^T + b[h]; A2 = x@Wf[h]^T + W_att[h]@b[h] = W_att@HX.
__global__ __launch_bounds__(256) void gat_fuse(
    const float* __restrict__ W_lin, const float* __restrict__ b_lin,
    const float* __restrict__ W_att,
    _Float16* __restrict__ Wall, float* __restrict__ ball)
{
    __shared__ float wl[128][8];
    const int h  = blockIdx.x >> 4;
    const int cb = blockIdx.x & 15;      // d-slice of 8
    const int t  = threadIdx.x;
    const float* WL = W_lin + h * F * F;
    const float* WA = W_att + h * F * F;

    {   // stage W_lin[:, cb*8 .. +8)
        int p = t >> 1, d0 = (t & 1) * 4;
        float4 v = *(const float4*)(WL + p * F + cb * 8 + d0);
        wl[p][d0+0]=v.x; wl[p][d0+1]=v.y; wl[p][d0+2]=v.z; wl[p][d0+3]=v.w;
    }
    __syncthreads();

    {   // Wf[o][cb*8+j2 .. +4) = sum_p W_att[o][p] * W_lin[p][d]
        int o = t >> 1, j2 = (t & 1) * 4;
        float a0=0, a1=0, a2=0, a3=0;
        const float* war = WA + o * F;
        #pragma unroll 4
        for (int p = 0; p < F; ++p) {
            float wa = war[p];
            a0 += wa * wl[p][j2+0]; a1 += wa * wl[p][j2+1];
            a2 += wa * wl[p][j2+2]; a3 += wa * wl[p][j2+3];
        }
        f16x4 hv; hv[0]=(_Float16)a0; hv[1]=(_Float16)a1;
        hv[2]=(_Float16)a2; hv[3]=(_Float16)a3;
        *(f16x4*)(Wall + (2*h+1) * F * F + o * F + cb * 8 + j2) = hv;
    }

    {   // convert W_lin slice to f16 (slot 2h)
        int idx = cb * 1024 + t * 4;
        float4 v = *(const float4*)(WL + idx);
        f16x4 hv; hv[0]=(_Float16)v.x; hv[1]=(_Float16)v.y;
        hv[2]=(_Float16)v.z; hv[3]=(_Float16)v.w;
        *(f16x4*)(Wall + 2*h * F * F + idx) = hv;
    }

    if (cb == 0 && t < F) {              // biases
        ball[2*h * F + t] = b_lin[h * F + t];
        float acc = 0;
        const float* war = WA + t * F;
        for (int p = 0; p < F; ++p) acc += war[p] * b_lin[h * F + p];
        ball[(2*h+1) * F + t] = acc;
    }
}

// ---------------- Kernel 2: single GEMM, M=50000 N=4x128 K=128 ----------------
// A-operand = weight slot (LDS, swizzled), B-operand = x rows (global f32->f16).
// D-frag: col(lane&15)=node, rows = 4 contiguous output features -> direct 8B stores.
__global__ __launch_bounds__(256) void gat_gemm(
    const float* __restrict__ x,        // [N][128]
    const _Float16* __restrict__ Wall,  // [4][128][128]
    const float* __restrict__ ball,     // [4][128]
    _Float16* __restrict__ HX,          // [N][2][128]
    _Float16* __restrict__ A2)          // [N][2][128]
{
    __shared__ _Float16 wbuf[F * F];    // 32 KB

    const int t    = threadIdx.x;
    const int lane = t & 63;
    const int r16  = lane & 15;
    const int kgrp = lane >> 4;
    const int slot = blockIdx.y;
    const int node_base = blockIdx.x * 64 + (t >> 6) * 16;

    // stage weight slot -> LDS f16 swizzled (pure f16x8 copy, coalesced)
    {
        const _Float16* Ws = Wall + slot * F * F;
        #pragma unroll
        for (int i = 0; i < 8; ++i) {
            int idx8 = i * 256 + t;             // 0..2047 chunks of 8 halfs
            int row  = idx8 >> 4;
            int colh = (idx8 & 15) * 8;
            *(f16x8*)(wbuf + swz(row, colh)) = *(const f16x8*)(Ws + idx8 * 8);
        }
    }

    // B-frags: this lane's x row (f32 -> f16)
    f16x8 xf[4];
    {
        int xrow = node_base + r16;
        if (xrow >= N_NODES) xrow = N_NODES - 1;
        const float* xp = x + (size_t)xrow * F + kgrp * 8;
        #pragma unroll
        for (int kk = 0; kk < 4; ++kk) {
            float4 v0 = *(const float4*)(xp + kk * 32);
            float4 v1 = *(const float4*)(xp + kk * 32 + 4);
            f16x8 hv;
            hv[0]=(_Float16)v0.x; hv[1]=(_Float16)v0.y;
            hv[2]=(_Float16)v0.z; hv[3]=(_Float16)v0.w;
            hv[4]=(_Float16)v1.x; hv[5]=(_Float16)v1.y;
            hv[6]=(_Float16)v1.z; hv[7]=(_Float16)v1.w;
            xf[kk] = hv;
        }
    }
    __syncthreads();

    const int node = node_base + r16;
    const bool ok  = node < N_NODES;
    _Float16* target = ((slot & 1) ? A2 : HX)
                     + (size_t)node * 256 + (slot >> 1) * F + kgrp * 4;

    #pragma unroll
    for (int c = 0; c < 8; ++c) {
        f32x4 acc = {0.f, 0.f, 0.f, 0.f};
        #pragma unroll
        for (int kk = 0; kk < 4; ++kk) {
            f16x8 aw = *(const f16x8*)(wbuf + swz(c * 16 + r16, kk * 32 + kgrp * 8));
            acc = __builtin_amdgcn_mfma_f32_16x16x32_f16(aw, xf[kk], acc, 0, 0, 0);
        }
        // bias for o = c*16 + kgrp*4 + r
        float4 bv = *(const float4*)(ball + slot * F + c * 16 + kgrp * 4);
        f16x4 hv;
        hv[0] = (_Float16)(acc[0] + bv.x);
        hv[1] = (_Float16)(acc[1] + bv.y);
        hv[2] = (_Float16)(acc[2] + bv.z);
        hv[3] = (_Float16)(acc[3] + bv.w);
        if (ok) *(f16x4*)(target + c * 16) = hv;
    }
}

// ---------------- Kernel 3: edge scores, 2 edges per wave ----------------
// score = dot(HX[row], A2[col]) over all 256 halfs (= sum of both heads);
// out = sigmoid(score/2). 32 lanes x 16B cover one edge side exactly.
__global__ __launch_bounds__(256) void gat_edge(
    const int* __restrict__ ei,          // [2][N_EDGES]
    const _Float16* __restrict__ HX,
    const _Float16* __restrict__ A2,
    float* __restrict__ out)
{
    int wid  = blockIdx.x * 4 + (threadIdx.x >> 6);
    int lane = threadIdx.x & 63;
    int e    = wid * 2 + (lane >> 5);
    int hl   = lane & 31;
    if (e >= N_EDGES) return;

    int r = ei[e];
    int c = ei[N_EDGES + e];

    f16x8 a = *(const f16x8*)(HX + (size_t)r * 256 + hl * 8);
    f16x8 b = *(const f16x8*)(A2 + (size_t)c * 256 + hl * 8);
    float p = 0.f;
    #pragma unroll
    for (int j = 0; j < 8; ++j) p += (float)a[j] * (float)b[j];

    #pragma unroll
    for (int m = 1; m <= 16; m <<= 1) p += __shfl_xor(p, m);

    if (hl == 0) out[e] = 1.f / (1.f + __expf(-0.5f * p));
}

extern "C" void kernel_launch(void* const* d_in, const int* in_sizes, int n_in,
                              void* d_out, int out_size, void* d_ws, size_t ws_size,
                              hipStream_t stream) {
    const float* x     = (const float*)d_in[0];
    const int*   ei    = (const int*)d_in[1];
    const float* W_lin = (const float*)d_in[2];
    const float* b_lin = (const float*)d_in[3];
    const float* W_att = (const float*)d_in[4];
    float* out = (float*)d_out;

    // workspace layout: Wall (128K halfs) | ball (512 f32) | HX | A2
    _Float16* Wall = (_Float16*)d_ws;
    float*    ball = (float*)(Wall + 4 * F * F);
    _Float16* HX   = (_Float16*)(ball + 4 * F);
    _Float16* A2   = HX + (size_t)N_NODES * 256;

    gat_fuse<<<32, 256, 0, stream>>>(W_lin, b_lin, W_att, Wall, ball);

    dim3 g2((N_NODES + 63) / 64, 4);     // 782 x 4 blocks
    gat_gemm<<<g2, 256, 0, stream>>>(x, Wall, ball, HX, A2);

    gat_edge<<<(N_EDGES + 7) / 8, 256, 0, stream>>>(ei, HX, A2, out);
}

// Round 5
// 97.226 us; speedup vs baseline: 2.7845x; 1.0559x over previous
//
#include <hip/hip_runtime.h>
#include <hip/hip_fp16.h>

constexpr int N_NODES = 50000;
constexpr int N_EDGES = 400000;
constexpr int F = 128;

typedef _Float16 f16x8 __attribute__((ext_vector_type(8)));
typedef _Float16 f16x4 __attribute__((ext_vector_type(4)));
typedef _Float16 f16x2 __attribute__((ext_vector_type(2)));
typedef float    f32x4 __attribute__((ext_vector_type(4)));

union v8v2 { f16x8 v8; f16x2 v2[4]; };

// XOR swizzle: flips half-index bits 3..5 by row&7 -> frag reads conflict-free.
__device__ __forceinline__ int swz(int row, int colh) {
    return (row * F + colh) ^ ((row & 7) << 3);
}

// ---------------- Kernel 1: weight fusion (tiny) ----------------
// Wall slots (f16 [128][128], natural [o][d]):
//   0: W_lin[0], 1: Wf[0]=W_att[0]@W_lin[0], 2: W_lin[1], 3: Wf[1]
// ball slots (f32 [128]): 0: b[0], 1: W_att[0]@b[0], 2: b[1], 3: W_att[1]@b[1]
// HX = x@W_lin[h]^T + b[h];  A2 = x@Wf[h]^T + W_att[h]@b[h] = W_att[h]@HX.
__global__ __launch_bounds__(256) void gat_fuse(
    const float* __restrict__ W_lin, const float* __restrict__ b_lin,
    const float* __restrict__ W_att,
    _Float16* __restrict__ Wall, float* __restrict__ ball)
{
    __shared__ float wl[128][8];
    const int h  = blockIdx.x >> 4;
    const int cb = blockIdx.x & 15;      // d-slice of 8
    const int t  = threadIdx.x;
    const float* WL = W_lin + h * F * F;
    const float* WA = W_att + h * F * F;

    {   // stage W_lin[:, cb*8 .. +8)
        int p = t >> 1, d0 = (t & 1) * 4;
        float4 v = *(const float4*)(WL + p * F + cb * 8 + d0);
        wl[p][d0+0]=v.x; wl[p][d0+1]=v.y; wl[p][d0+2]=v.z; wl[p][d0+3]=v.w;
    }
    __syncthreads();

    {   // Wf[o][cb*8+j2 .. +4) = sum_p W_att[o][p] * W_lin[p][d]
        int o = t >> 1, j2 = (t & 1) * 4;
        float a0=0, a1=0, a2=0, a3=0;
        const float* war = WA + o * F;
        #pragma unroll 4
        for (int p = 0; p < F; ++p) {
            float wa = war[p];
            a0 += wa * wl[p][j2+0]; a1 += wa * wl[p][j2+1];
            a2 += wa * wl[p][j2+2]; a3 += wa * wl[p][j2+3];
        }
        f16x4 hv; hv[0]=(_Float16)a0; hv[1]=(_Float16)a1;
        hv[2]=(_Float16)a2; hv[3]=(_Float16)a3;
        *(f16x4*)(Wall + (2*h+1) * F * F + o * F + cb * 8 + j2) = hv;
    }

    {   // convert W_lin slice to f16 (slot 2h)
        int idx = cb * 1024 + t * 4;
        float4 v = *(const float4*)(WL + idx);
        f16x4 hv; hv[0]=(_Float16)v.x; hv[1]=(_Float16)v.y;
        hv[2]=(_Float16)v.z; hv[3]=(_Float16)v.w;
        *(f16x4*)(Wall + 2*h * F * F + idx) = hv;
    }

    if (cb == 0 && t < F) {              // biases
        ball[2*h * F + t] = b_lin[h * F + t];
        float acc = 0;
        const float* war = WA + t * F;
        for (int p = 0; p < F; ++p) acc += war[p] * b_lin[h * F + p];
        ball[(2*h+1) * F + t] = acc;
    }
}

// ---------------- Kernel 2: GEMM, M=50000, 4 weight slots looped in-block ----
// x rows live in regs across all 4 slots; weights staged per slot in 32KB LDS.
__global__ __launch_bounds__(256) void gat_gemm(
    const float* __restrict__ x,        // [N][128]
    const _Float16* __restrict__ Wall,  // [4][128][128]
    const float* __restrict__ ball,     // [4][128]
    _Float16* __restrict__ HX,          // [N][2][128]
    _Float16* __restrict__ A2)          // [N][2][128]
{
    __shared__ _Float16 wbuf[F * F];    // 32 KB

    const int t    = threadIdx.x;
    const int lane = t & 63;
    const int r16  = lane & 15;
    const int kgrp = lane >> 4;
    const int node_base = blockIdx.x * 64 + (t >> 6) * 16;

    // B-frags: this lane's x row (f32 -> f16), persistent across slots
    f16x8 xf[4];
    {
        int xrow = node_base + r16;
        if (xrow >= N_NODES) xrow = N_NODES - 1;
        const float* xp = x + (size_t)xrow * F + kgrp * 8;
        #pragma unroll
        for (int kk = 0; kk < 4; ++kk) {
            float4 v0 = *(const float4*)(xp + kk * 32);
            float4 v1 = *(const float4*)(xp + kk * 32 + 4);
            f16x8 hv;
            hv[0]=(_Float16)v0.x; hv[1]=(_Float16)v0.y;
            hv[2]=(_Float16)v0.z; hv[3]=(_Float16)v0.w;
            hv[4]=(_Float16)v1.x; hv[5]=(_Float16)v1.y;
            hv[6]=(_Float16)v1.z; hv[7]=(_Float16)v1.w;
            xf[kk] = hv;
        }
    }

    const int node = node_base + r16;
    const bool ok  = node < N_NODES;

    #pragma unroll
    for (int slot = 0; slot < 4; ++slot) {
        if (slot) __syncthreads();          // waves done reading prev slot
        {   // stage weight slot -> LDS f16 swizzled (f16x8 copy, coalesced)
            const _Float16* Ws = Wall + slot * F * F;
            #pragma unroll
            for (int i = 0; i < 8; ++i) {
                int idx8 = i * 256 + t;
                int row  = idx8 >> 4;
                int colh = (idx8 & 15) * 8;
                *(f16x8*)(wbuf + swz(row, colh)) = *(const f16x8*)(Ws + idx8 * 8);
            }
        }
        __syncthreads();

        _Float16* target = ((slot & 1) ? A2 : HX)
                         + (size_t)node * 256 + (slot >> 1) * F + kgrp * 4;

        #pragma unroll
        for (int c = 0; c < 8; ++c) {
            f32x4 acc = {0.f, 0.f, 0.f, 0.f};
            #pragma unroll
            for (int kk = 0; kk < 4; ++kk) {
                f16x8 aw = *(const f16x8*)(wbuf + swz(c * 16 + r16, kk * 32 + kgrp * 8));
                acc = __builtin_amdgcn_mfma_f32_16x16x32_f16(aw, xf[kk], acc, 0, 0, 0);
            }
            float4 bv = *(const float4*)(ball + slot * F + c * 16 + kgrp * 4);
            f16x4 hv;
            hv[0] = (_Float16)(acc[0] + bv.x);
            hv[1] = (_Float16)(acc[1] + bv.y);
            hv[2] = (_Float16)(acc[2] + bv.z);
            hv[3] = (_Float16)(acc[3] + bv.w);
            if (ok) *(f16x4*)(target + c * 16) = hv;
        }
    }
}

// ---------------- Kernel 3: edge scores, 4 edges/wave, fdot2 ----------------
// 16-lane group per edge: 32 B/lane/side. score = dot(HX[r], A2[c]) over 256
// halfs (sums both heads); out = sigmoid(score/2).
__global__ __launch_bounds__(256) void gat_edge(
    const int* __restrict__ ei,          // [2][N_EDGES]
    const _Float16* __restrict__ HX,
    const _Float16* __restrict__ A2,
    float* __restrict__ out)
{
    int wid  = blockIdx.x * 4 + (threadIdx.x >> 6);
    int lane = threadIdx.x & 63;
    int e    = wid * 4 + (lane >> 4);
    int hl   = lane & 15;
    if (e >= N_EDGES) return;

    int r = ei[e];
    int c = ei[N_EDGES + e];

    const _Float16* hp = HX + (size_t)r * 256 + hl * 8;
    const _Float16* ap = A2 + (size_t)c * 256 + hl * 8;
    v8v2 a0, a1, b0, b1;
    a0.v8 = *(const f16x8*)(hp);
    a1.v8 = *(const f16x8*)(hp + 128);
    b0.v8 = *(const f16x8*)(ap);
    b1.v8 = *(const f16x8*)(ap + 128);

    float p = 0.f;
    #pragma unroll
    for (int j = 0; j < 4; ++j) {
        p = __builtin_amdgcn_fdot2(a0.v2[j], b0.v2[j], p, false);
        p = __builtin_amdgcn_fdot2(a1.v2[j], b1.v2[j], p, false);
    }

    #pragma unroll
    for (int m = 1; m <= 8; m <<= 1) p += __shfl_xor(p, m);

    if (hl == 0) out[e] = 1.f / (1.f + __expf(-0.5f * p));
}

extern "C" void kernel_launch(void* const* d_in, const int* in_sizes, int n_in,
                              void* d_out, int out_size, void* d_ws, size_t ws_size,
                              hipStream_t stream) {
    const float* x     = (const float*)d_in[0];
    const int*   ei    = (const int*)d_in[1];
    const float* W_lin = (const float*)d_in[2];
    const float* b_lin = (const float*)d_in[3];
    const float* W_att = (const float*)d_in[4];
    float* out = (float*)d_out;

    // workspace layout: Wall (128K halfs) | ball (512 f32) | HX | A2
    _Float16* Wall = (_Float16*)d_ws;
    float*    ball = (float*)(Wall + 4 * F * F);
    _Float16* HX   = (_Float16*)(ball + 4 * F);
    _Float16* A2   = HX + (size_t)N_NODES * 256;

    gat_fuse<<<32, 256, 0, stream>>>(W_lin, b_lin, W_att, Wall, ball);

    gat_gemm<<<(N_NODES + 63) / 64, 256, 0, stream>>>(x, Wall, ball, HX, A2);

    gat_edge<<<N_EDGES / 16, 256, 0, stream>>>(ei, HX, A2, out);
}

// Round 6
// 93.434 us; speedup vs baseline: 2.8976x; 1.0406x over previous
//
#include <hip/hip_runtime.h>
#include <hip/hip_fp16.h>

constexpr int N_NODES = 50000;
constexpr int N_EDGES = 400000;
constexpr int F = 128;

typedef _Float16 f16x8 __attribute__((ext_vector_type(8)));
typedef _Float16 f16x4 __attribute__((ext_vector_type(4)));
typedef _Float16 f16x2 __attribute__((ext_vector_type(2)));
typedef float    f32x4 __attribute__((ext_vector_type(4)));

union v8v2 { f16x8 v8; f16x2 v2[4]; };

// XOR swizzle: flips half-index bits 3..5 by row&7 -> frag reads conflict-free.
__device__ __forceinline__ int swz(int row, int colh) {
    return (row * F + colh) ^ ((row & 7) << 3);
}

// ---------------- Kernel 1: weight fusion (tiny) ----------------
// Wall slots (f16 [128][128], natural [o][d]):
//   0: W_lin[0], 1: Wf[0]=W_att[0]@W_lin[0], 2: W_lin[1], 3: Wf[1]
// ball slots (f32 [128]): 0: b[0], 1: W_att[0]@b[0], 2: b[1], 3: W_att[1]@b[1]
// HX = x@W_lin[h]^T + b[h];  A2 = x@Wf[h]^T + W_att[h]@b[h] = W_att[h]@HX.
__global__ __launch_bounds__(256) void gat_fuse(
    const float* __restrict__ W_lin, const float* __restrict__ b_lin,
    const float* __restrict__ W_att,
    _Float16* __restrict__ Wall, float* __restrict__ ball)
{
    __shared__ float wl[128][8];
    const int h  = blockIdx.x >> 4;
    const int cb = blockIdx.x & 15;      // d-slice of 8
    const int t  = threadIdx.x;
    const float* WL = W_lin + h * F * F;
    const float* WA = W_att + h * F * F;

    {   // stage W_lin[:, cb*8 .. +8)
        int p = t >> 1, d0 = (t & 1) * 4;
        float4 v = *(const float4*)(WL + p * F + cb * 8 + d0);
        wl[p][d0+0]=v.x; wl[p][d0+1]=v.y; wl[p][d0+2]=v.z; wl[p][d0+3]=v.w;
    }
    __syncthreads();

    {   // Wf[o][cb*8+j2 .. +4) = sum_p W_att[o][p] * W_lin[p][d]
        int o = t >> 1, j2 = (t & 1) * 4;
        float a0=0, a1=0, a2=0, a3=0;
        const float* war = WA + o * F;
        #pragma unroll 4
        for (int p = 0; p < F; ++p) {
            float wa = war[p];
            a0 += wa * wl[p][j2+0]; a1 += wa * wl[p][j2+1];
            a2 += wa * wl[p][j2+2]; a3 += wa * wl[p][j2+3];
        }
        f16x4 hv; hv[0]=(_Float16)a0; hv[1]=(_Float16)a1;
        hv[2]=(_Float16)a2; hv[3]=(_Float16)a3;
        *(f16x4*)(Wall + (2*h+1) * F * F + o * F + cb * 8 + j2) = hv;
    }

    {   // convert W_lin slice to f16 (slot 2h)
        int idx = cb * 1024 + t * 4;
        float4 v = *(const float4*)(WL + idx);
        f16x4 hv; hv[0]=(_Float16)v.x; hv[1]=(_Float16)v.y;
        hv[2]=(_Float16)v.z; hv[3]=(_Float16)v.w;
        *(f16x4*)(Wall + 2*h * F * F + idx) = hv;
    }

    if (cb == 0 && t < F) {              // biases
        ball[2*h * F + t] = b_lin[h * F + t];
        float acc = 0;
        const float* war = WA + t * F;
        for (int p = 0; p < F; ++p) acc += war[p] * b_lin[h * F + p];
        ball[(2*h+1) * F + t] = acc;
    }
}

// ---------------- Kernel 2: GEMM, 128 nodes/block, 32 nodes/wave ----------
// x rows live in regs across all 4 weight slots; weights staged per slot in
// 32KB LDS; aw frags shared across the wave's 2 node-groups.
__global__ __launch_bounds__(256) void gat_gemm(
    const float* __restrict__ x,        // [N][128]
    const _Float16* __restrict__ Wall,  // [4][128][128]
    const float* __restrict__ ball,     // [4][128]
    _Float16* __restrict__ HX,          // [N][2][128]
    _Float16* __restrict__ A2)          // [N][2][128]
{
    __shared__ _Float16 wbuf[F * F];    // 32 KB

    const int t    = threadIdx.x;
    const int lane = t & 63;
    const int r16  = lane & 15;
    const int kgrp = lane >> 4;
    const int node_base = blockIdx.x * 128 + (t >> 6) * 32;

    // B-frags: 2 node groups of 16, f32 -> f16, persistent across slots
    f16x8 xf[2][4];
    #pragma unroll
    for (int g = 0; g < 2; ++g) {
        int xrow = node_base + g * 16 + r16;
        if (xrow >= N_NODES) xrow = N_NODES - 1;
        const float* xp = x + (size_t)xrow * F + kgrp * 8;
        #pragma unroll
        for (int kk = 0; kk < 4; ++kk) {
            float4 v0 = *(const float4*)(xp + kk * 32);
            float4 v1 = *(const float4*)(xp + kk * 32 + 4);
            f16x8 hv;
            hv[0]=(_Float16)v0.x; hv[1]=(_Float16)v0.y;
            hv[2]=(_Float16)v0.z; hv[3]=(_Float16)v0.w;
            hv[4]=(_Float16)v1.x; hv[5]=(_Float16)v1.y;
            hv[6]=(_Float16)v1.z; hv[7]=(_Float16)v1.w;
            xf[g][kk] = hv;
        }
    }

    #pragma unroll
    for (int slot = 0; slot < 4; ++slot) {
        if (slot) __syncthreads();          // waves done reading prev slot
        {   // stage weight slot -> LDS f16 swizzled (f16x8 copy, coalesced)
            const _Float16* Ws = Wall + slot * F * F;
            #pragma unroll
            for (int i = 0; i < 8; ++i) {
                int idx8 = i * 256 + t;
                int row  = idx8 >> 4;
                int colh = (idx8 & 15) * 8;
                *(f16x8*)(wbuf + swz(row, colh)) = *(const f16x8*)(Ws + idx8 * 8);
            }
        }
        __syncthreads();

        #pragma unroll
        for (int c = 0; c < 8; ++c) {
            f16x8 aw[4];
            #pragma unroll
            for (int kk = 0; kk < 4; ++kk)
                aw[kk] = *(const f16x8*)(wbuf + swz(c * 16 + r16, kk * 32 + kgrp * 8));
            float4 bv = *(const float4*)(ball + slot * F + c * 16 + kgrp * 4);

            #pragma unroll
            for (int g = 0; g < 2; ++g) {
                f32x4 acc = {0.f, 0.f, 0.f, 0.f};
                #pragma unroll
                for (int kk = 0; kk < 4; ++kk)
                    acc = __builtin_amdgcn_mfma_f32_16x16x32_f16(aw[kk], xf[g][kk], acc, 0, 0, 0);
                int node = node_base + g * 16 + r16;
                f16x4 hv;
                hv[0] = (_Float16)(acc[0] + bv.x);
                hv[1] = (_Float16)(acc[1] + bv.y);
                hv[2] = (_Float16)(acc[2] + bv.z);
                hv[3] = (_Float16)(acc[3] + bv.w);
                if (node < N_NODES) {
                    _Float16* target = ((slot & 1) ? A2 : HX)
                        + (size_t)node * 256 + (slot >> 1) * F + kgrp * 4;
                    *(f16x4*)(target + c * 16) = hv;
                }
            }
        }
    }
}

// ---------------- Kernel 3: edge scores, 8 edges/wave, 8 lanes/edge --------
// 64B/lane/side = 8x16B loads in flight per lane (2x MLP vs R5).
// score = dot(HX[r], A2[c]) over 256 halfs; out = sigmoid(score/2).
__global__ __launch_bounds__(256) void gat_edge(
    const int* __restrict__ ei,          // [2][N_EDGES]
    const _Float16* __restrict__ HX,
    const _Float16* __restrict__ A2,
    float* __restrict__ out)
{
    int wid  = blockIdx.x * 4 + (threadIdx.x >> 6);
    int lane = threadIdx.x & 63;
    int e    = wid * 8 + (lane >> 3);
    int hl   = lane & 7;
    if (e >= N_EDGES) return;

    int r = ei[e];
    int c = ei[N_EDGES + e];

    const _Float16* hp = HX + (size_t)r * 256 + hl * 32;
    const _Float16* ap = A2 + (size_t)c * 256 + hl * 32;
    v8v2 a[4], b[4];
    #pragma unroll
    for (int i = 0; i < 4; ++i) a[i].v8 = *(const f16x8*)(hp + i * 8);
    #pragma unroll
    for (int i = 0; i < 4; ++i) b[i].v8 = *(const f16x8*)(ap + i * 8);

    float p = 0.f;
    #pragma unroll
    for (int i = 0; i < 4; ++i)
        #pragma unroll
        for (int j = 0; j < 4; ++j)
            p = __builtin_amdgcn_fdot2(a[i].v2[j], b[i].v2[j], p, false);

    #pragma unroll
    for (int m = 1; m <= 4; m <<= 1) p += __shfl_xor(p, m);

    if (hl == 0) out[e] = 1.f / (1.f + __expf(-0.5f * p));
}

extern "C" void kernel_launch(void* const* d_in, const int* in_sizes, int n_in,
                              void* d_out, int out_size, void* d_ws, size_t ws_size,
                              hipStream_t stream) {
    const float* x     = (const float*)d_in[0];
    const int*   ei    = (const int*)d_in[1];
    const float* W_lin = (const float*)d_in[2];
    const float* b_lin = (const float*)d_in[3];
    const float* W_att = (const float*)d_in[4];
    float* out = (float*)d_out;

    // workspace layout: Wall (128K halfs) | ball (512 f32) | HX | A2
    _Float16* Wall = (_Float16*)d_ws;
    float*    ball = (float*)(Wall + 4 * F * F);
    _Float16* HX   = (_Float16*)(ball + 4 * F);
    _Float16* A2   = HX + (size_t)N_NODES * 256;

    gat_fuse<<<32, 256, 0, stream>>>(W_lin, b_lin, W_att, Wall, ball);

    gat_gemm<<<(N_NODES + 127) / 128, 256, 0, stream>>>(x, Wall, ball, HX, A2);

    gat_edge<<<N_EDGES / 32, 256, 0, stream>>>(ei, HX, A2, out);
}